// Round 1
// baseline (959.644 us; speedup 1.0000x reference)
//
#include <hip/hip_runtime.h>
#include <math.h>

typedef __bf16 bf16x8 __attribute__((ext_vector_type(8)));
typedef float f32x4 __attribute__((ext_vector_type(4)));
typedef unsigned short u16;
typedef unsigned int u32;

#define T_SEQ 2048
#define NHEAD 32

// float -> bf16 bits, round-nearest-even
__device__ __forceinline__ u16 f2bu(float f){
  u32 u = __float_as_uint(f);
  u32 r = (u + 0x7fffu + ((u >> 16) & 1u)) >> 16;
  return (u16)r;
}

__device__ __forceinline__ void gload_lds16(const void* g, void* l){
  __builtin_amdgcn_global_load_lds((const __attribute__((address_space(1))) u32*)g,
                                   (__attribute__((address_space(3))) u32*)l, 16, 0, 0);
}

// ---------------- elementwise cast f32 -> bf16 (vector4) ----------------
__global__ void cast_f32_bf16(const float* __restrict__ in, u16* __restrict__ out, int n4){
  int i = blockIdx.x * blockDim.x + threadIdx.x;
  int stride = gridDim.x * blockDim.x;
  for (; i < n4; i += stride){
    float4 v = ((const float4*)in)[i];
    ushort4 o;
    o.x = f2bu(v.x); o.y = f2bu(v.y); o.z = f2bu(v.z); o.w = f2bu(v.w);
    ((ushort4*)out)[i] = o;
  }
}

// ---------------- transpose + cast: src f32 (K x N) -> dst bf16 (Npad x K) ----------------
// rows n >= N are zero-filled.  K multiple of 64, Npad multiple of 64.
__global__ void transpose_cast(const float* __restrict__ src, u16* __restrict__ dst,
                               int K, int N){
  __shared__ float tile[64][65];
  int k0 = blockIdx.x * 64, n0 = blockIdx.y * 64;
  int lr = threadIdx.x >> 6, lc = threadIdx.x & 63;
  #pragma unroll
  for (int i = 0; i < 16; i++){
    int r = lr * 16 + i;
    int n = n0 + lc;
    float v = (n < N) ? src[(size_t)(k0 + r) * N + n] : 0.f;
    tile[r][lc] = v;
  }
  __syncthreads();
  #pragma unroll
  for (int i = 0; i < 16; i++){
    int nr = lr * 16 + i;
    dst[(size_t)(n0 + nr) * K + k0 + lc] = f2bu(tile[lc][nr]);
  }
}

// ---------------- YaRN rope table ----------------
__global__ void rope_table(const int* __restrict__ positions, float* __restrict__ cosT,
                           float* __restrict__ sinT, float lo, float denom){
  int idx = blockIdx.x * blockDim.x + threadIdx.x;
  if (idx >= T_SEQ * 32) return;
  int t = idx >> 5, i = idx & 31;
  float pf = powf(10000.f, (float)i / 32.f);
  float inv_extra = 1.f / pf;
  float inv_inter = 1.f / (40.f * pf);
  float ramp = fminf(fmaxf(((float)i - lo) / denom, 0.f), 1.f);
  // inv_freq = inv_inter*ramp + inv_extra*(1-ramp)
  float invf = inv_inter * ramp + inv_extra * (1.f - ramp);
  float fr = (float)positions[t] * invf;
  cosT[idx] = cosf(fr);
  sinT[idx] = sinf(fr);
}

// ---------------- rmsnorm (f32 in, bf16 out) ----------------
__global__ void rmsnorm_cast(const float* __restrict__ in, int istride, int n,
                             const float* __restrict__ w, u16* __restrict__ out, int ostride){
  int row = blockIdx.x;
  const float* x = in + (size_t)row * istride;
  float ss = 0.f;
  for (int c = threadIdx.x; c < n; c += blockDim.x){ float v = x[c]; ss += v * v; }
  #pragma unroll
  for (int off = 1; off < 64; off <<= 1) ss += __shfl_xor(ss, off);
  __shared__ float wsum[4];
  if ((threadIdx.x & 63) == 0) wsum[threadIdx.x >> 6] = ss;
  __syncthreads();
  float tot = wsum[0] + wsum[1] + wsum[2] + wsum[3];
  float scale = rsqrtf(tot / (float)n + 1e-6f);
  for (int c = threadIdx.x; c < n; c += blockDim.x)
    out[(size_t)row * ostride + c] = f2bu(x[c] * scale * w[c]);
}

// ---------------- rope on k_pe (from latent cols 512..575, stride 640) ----------------
__global__ void rope_kpe(const float* __restrict__ latent, const float* __restrict__ cosT,
                         const float* __restrict__ sinT, u16* __restrict__ kpe){
  int idx = blockIdx.x * blockDim.x + threadIdx.x;
  if (idx >= T_SEQ * 32) return;
  int t = idx >> 5, i = idx & 31;
  float x1 = latent[(size_t)t * 640 + 512 + 2 * i];
  float x2 = latent[(size_t)t * 640 + 512 + 2 * i + 1];
  float c = cosT[idx], s = sinT[idx];
  kpe[t * 64 + 2 * i]     = f2bu(x1 * c - x2 * s);
  kpe[t * 64 + 2 * i + 1] = f2bu(x2 * c + x1 * s);
}

// ---------------- build Q' (H,T,192) bf16: rope on dims 128..191, * scaling ----------------
__global__ void build_q(const float* __restrict__ qfull, const float* __restrict__ cosT,
                        const float* __restrict__ sinT, u16* __restrict__ Qp, float scaling){
  const int total = NHEAD * T_SEQ * 192;
  for (int idx = blockIdx.x * blockDim.x + threadIdx.x; idx < total; idx += gridDim.x * blockDim.x){
    int h = idx / (T_SEQ * 192);
    int rem = idx - h * (T_SEQ * 192);
    int t = rem / 192, d = rem - t * 192;
    float v;
    if (d < 128){
      v = qfull[(size_t)t * 6144 + h * 192 + d];
    } else {
      int i = (d - 128) >> 1;
      float c = cosT[t * 32 + i], s = sinT[t * 32 + i];
      float x1 = qfull[(size_t)t * 6144 + h * 192 + 128 + 2 * i];
      float x2 = qfull[(size_t)t * 6144 + h * 192 + 128 + 2 * i + 1];
      v = ((d & 1) == 0) ? (x1 * c - x2 * s) : (x2 * c + x1 * s);
    }
    Qp[idx] = f2bu(v * scaling);
  }
}

// ---------------- build K' (H,T,192) bf16: k_nope | k_pe broadcast ----------------
__global__ void build_k(const float* __restrict__ kvfull, const u16* __restrict__ kpe,
                        u16* __restrict__ Kp){
  const int total = NHEAD * T_SEQ * 192;
  for (int idx = blockIdx.x * blockDim.x + threadIdx.x; idx < total; idx += gridDim.x * blockDim.x){
    int h = idx / (T_SEQ * 192);
    int rem = idx - h * (T_SEQ * 192);
    int t = rem / 192, d = rem - t * 192;
    if (d < 128) Kp[idx] = f2bu(kvfull[(size_t)t * 8192 + h * 256 + d]);
    else         Kp[idx] = kpe[t * 64 + (d - 128)];
  }
}

// ---------------- build Vt (H,128,T) bf16 (transposed V) ----------------
__global__ void build_vt(const float* __restrict__ kvfull, u16* __restrict__ Vt){
  __shared__ u16 tile[128][72];
  int t0 = blockIdx.x * 64;
  int h = blockIdx.y;
  #pragma unroll
  for (int i = 0; i < 32; i++){
    int lin = threadIdx.x + i * 256;
    int tt = lin >> 7, dd = lin & 127;
    tile[dd][tt] = f2bu(kvfull[(size_t)(t0 + tt) * 8192 + h * 256 + 128 + dd]);
  }
  __syncthreads();
  #pragma unroll
  for (int i = 0; i < 32; i++){
    int lin = threadIdx.x + i * 256;
    int dd = lin >> 6, tt = lin & 63;
    Vt[(size_t)(h * 128 + dd) * T_SEQ + t0 + tt] = tile[dd][tt];
  }
}

// ---------------- GEMM: C[M,N] f32 = A[M,K]bf16 @ BT[N,K]bf16^T ----------------
// 128x128 tile, BK=32, 4 waves (2x2), global_load_lds staging, XOR-swizzled LDS.
__global__ __launch_bounds__(256) void gemm_bt(const u16* __restrict__ A, const u16* __restrict__ BT,
                                               float* __restrict__ C, int M, int N, int K){
  __shared__ __align__(1024) char lds[16384];
  char* ldsA = lds;
  char* ldsB = lds + 8192;
  const int tid = threadIdx.x;
  const int wave = tid >> 6, lane = tid & 63;
  const int lg = lane >> 4, lm = lane & 15;
  const int bm = blockIdx.y * 128, bn = blockIdx.x * 128;
  const int wr = (wave >> 1) * 64, wc = (wave & 1) * 64;
  f32x4 acc[4][4] = {};
  int srow[2], scol[2], soff[2];
  #pragma unroll
  for (int j = 0; j < 2; j++){
    int o = (wave * 2 + j) * 1024 + lane * 16;
    int row = o >> 6;
    int cg = ((o >> 4) & 3) ^ ((row >> 1) & 3);   // inverse (== forward) swizzle on source
    srow[j] = row; scol[j] = cg * 8; soff[j] = (wave * 2 + j) * 1024;
  }
  for (int k0 = 0; k0 < K; k0 += 32){
    #pragma unroll
    for (int j = 0; j < 2; j++){
      gload_lds16(A  + (size_t)(bm + srow[j]) * K + k0 + scol[j], ldsA + soff[j]);
      gload_lds16(BT + (size_t)(bn + srow[j]) * K + k0 + scol[j], ldsB + soff[j]);
    }
    __syncthreads();
    bf16x8 af[4], bfr[4];
    #pragma unroll
    for (int m = 0; m < 4; m++){
      int r = wr + m * 16 + lm;
      af[m] = *(const bf16x8*)(ldsA + r * 64 + ((lg ^ ((r >> 1) & 3)) << 4));
    }
    #pragma unroll
    for (int n = 0; n < 4; n++){
      int r = wc + n * 16 + lm;
      bfr[n] = *(const bf16x8*)(ldsB + r * 64 + ((lg ^ ((r >> 1) & 3)) << 4));
    }
    #pragma unroll
    for (int m = 0; m < 4; m++)
      #pragma unroll
      for (int n = 0; n < 4; n++)
        acc[m][n] = __builtin_amdgcn_mfma_f32_16x16x32_bf16(af[m], bfr[n], acc[m][n], 0, 0, 0);
    __syncthreads();
  }
  #pragma unroll
  for (int m = 0; m < 4; m++)
    #pragma unroll
    for (int n = 0; n < 4; n++)
      #pragma unroll
      for (int q = 0; q < 4; q++){
        int r = bm + wr + m * 16 + lg * 4 + q;
        int c = bn + wc + n * 16 + lm;
        C[(size_t)r * N + c] = acc[m][n][q];
      }
}

// ---------------- flash attention: 1 wave per (head, 16 q rows) ----------------
__global__ __launch_bounds__(64) void flash_attn(const u16* __restrict__ Qp, const u16* __restrict__ Kp,
                                                 const u16* __restrict__ Vt, u16* __restrict__ attnb){
  const int qt = blockIdx.x, h = blockIdx.y;
  const int lane = threadIdx.x;
  const int lg = lane >> 4, lm = lane & 15;
  __shared__ __align__(16) u16 P[16 * 40];

  bf16x8 qf[6];
  const u16* Qbase = Qp + (size_t)(h * T_SEQ + qt * 16 + lm) * 192 + lg * 8;
  #pragma unroll
  for (int dk = 0; dk < 6; dk++) qf[dk] = *(const bf16x8*)(Qbase + dk * 32);

  f32x4 o[8] = {};
  float m_[4], l_[4];
  #pragma unroll
  for (int q = 0; q < 4; q++){ m_[q] = -3.0e38f; l_[q] = 0.f; }

  const int ktiles = (qt * 16 + 47) >> 5;
  for (int kt = 0; kt < ktiles; kt++){
    const int t0 = kt * 32;
    f32x4 s[2] = {};
    #pragma unroll
    for (int half = 0; half < 2; half++){
      const u16* Kbase = Kp + (size_t)(h * T_SEQ + t0 + half * 16 + lm) * 192 + lg * 8;
      #pragma unroll
      for (int dk = 0; dk < 6; dk++){
        bf16x8 kf = *(const bf16x8*)(Kbase + dk * 32);
        s[half] = __builtin_amdgcn_mfma_f32_16x16x32_bf16(qf[dk], kf, s[half], 0, 0, 0);
      }
    }
    // causal mask
    #pragma unroll
    for (int half = 0; half < 2; half++)
      #pragma unroll
      for (int q = 0; q < 4; q++){
        int col = t0 + half * 16 + lm;
        int qrow = qt * 16 + lg * 4 + q;
        if (col > qrow) s[half][q] = -3.0e38f;
      }
    // online softmax
    #pragma unroll
    for (int q = 0; q < 4; q++){
      float v = fmaxf(s[0][q], s[1][q]);
      #pragma unroll
      for (int off = 8; off; off >>= 1) v = fmaxf(v, __shfl_xor(v, off));
      float mn = fmaxf(m_[q], v);
      float alpha = (m_[q] <= -1.0e37f) ? 0.f : __expf(m_[q] - mn);
      float p0 = __expf(s[0][q] - mn);
      float p1 = __expf(s[1][q] - mn);
      float rs = p0 + p1;
      #pragma unroll
      for (int off = 8; off; off >>= 1) rs += __shfl_xor(rs, off);
      l_[q] = l_[q] * alpha + rs;
      m_[q] = mn;
      #pragma unroll
      for (int n = 0; n < 8; n++) o[n][q] *= alpha;
      P[(lg * 4 + q) * 40 + lm]      = f2bu(p0);
      P[(lg * 4 + q) * 40 + 16 + lm] = f2bu(p1);
    }
    asm volatile("s_waitcnt lgkmcnt(0)" ::: "memory");
    bf16x8 pf = *(const bf16x8*)(P + lm * 40 + lg * 8);
    #pragma unroll
    for (int n = 0; n < 8; n++){
      const u16* Vbase = Vt + (size_t)(h * 128 + n * 16 + lm) * T_SEQ + t0 + lg * 8;
      bf16x8 vf = *(const bf16x8*)Vbase;
      o[n] = __builtin_amdgcn_mfma_f32_16x16x32_bf16(pf, vf, o[n], 0, 0, 0);
    }
  }
  float inv[4];
  #pragma unroll
  for (int q = 0; q < 4; q++) inv[q] = 1.f / l_[q];
  #pragma unroll
  for (int n = 0; n < 8; n++)
    #pragma unroll
    for (int q = 0; q < 4; q++){
      int r = qt * 16 + lg * 4 + q;
      attnb[(size_t)r * 4096 + h * 128 + n * 16 + lm] = f2bu(o[n][q] * inv[q]);
    }
}

// =====================================================================
extern "C" void kernel_launch(void* const* d_in, const int* in_sizes, int n_in,
                              void* d_out, int out_size, void* d_ws, size_t ws_size,
                              hipStream_t stream){
  const int*   positions = (const int*)d_in[0];
  const float* hidden    = (const float*)d_in[1];
  const float* Wqa       = (const float*)d_in[2];
  const float* q_a_ln    = (const float*)d_in[3];
  const float* Wqb       = (const float*)d_in[4];
  const float* Wkva      = (const float*)d_in[5];
  const float* kv_a_ln   = (const float*)d_in[6];
  const float* Wkvb      = (const float*)d_in[7];
  const float* Wo        = (const float*)d_in[8];
  float* out = (float*)d_out;
  char* ws = (char*)d_ws;

  // workspace layout (bytes); peak = 211,550,208 (~202 MiB)
  const size_t o_hid   = 0;          // bf16 2048x4096 (dead after gemm latent)
  const size_t o_cos   = 16777216;   // f32 2048x32
  const size_t o_sin   = 17039360;
  const size_t o_qlat  = 17301504;   // f32 2048x1536 (dead after rmsnorm)
  const size_t o_qln   = 29884416;   // bf16 2048x1536 (dead after gemm q)
  const size_t o_lat   = 36175872;   // f32 2048x640
  const size_t o_kva   = 41418752;   // bf16 2048x512 (dead after gemm kv)
  const size_t o_kpe   = 43515904;   // bf16 2048x64
  const size_t o_W     = 43778048;   // bf16 weight scratch (<= 33.55 MB, reused 5x)
  const size_t o_qfull = 77332480;   // f32 2048x6144 (dead after build_q)
  const size_t o_kvf   = 127664128;  // f32 2048x8192 (dead after build_vt)
  const size_t o_Qp    = 17301504;   // bf16 32x2048x192 (aliases qlat.., ends 42467328)
  const size_t o_Kp    = 77332480;   // bf16 32x2048x192 (aliases qfull, ends 102498304)
  const size_t o_att   = 102498304;  // bf16 2048x4096 (ends 119275520)
  const size_t o_Vt    = 194772992;  // bf16 32x128x2048 (ends 211550208)

  u16*   hidB   = (u16*)(ws + o_hid);
  float* cosT   = (float*)(ws + o_cos);
  float* sinT   = (float*)(ws + o_sin);
  float* qlat   = (float*)(ws + o_qlat);
  u16*   qln    = (u16*)(ws + o_qln);
  float* latent = (float*)(ws + o_lat);
  u16*   kva    = (u16*)(ws + o_kva);
  u16*   kpe    = (u16*)(ws + o_kpe);
  u16*   Wt     = (u16*)(ws + o_W);
  float* qfull  = (float*)(ws + o_qfull);
  float* kvfull = (float*)(ws + o_kvf);
  u16*   Qp     = (u16*)(ws + o_Qp);
  u16*   Kp     = (u16*)(ws + o_Kp);
  u16*   attnb  = (u16*)(ws + o_att);
  u16*   Vt     = (u16*)(ws + o_Vt);

  // host-side constants
  double mscale = 0.1 * log(40.0) + 1.0;
  float scaling = (float)(pow(192.0, -0.5) * mscale * mscale);
  const double PI = 3.14159265358979323846;
  double cd_fast = 64.0 * log(4096.0 / (32.0 * 2.0 * PI)) / (2.0 * log(10000.0));
  double cd_slow = 64.0 * log(4096.0 / ( 1.0 * 2.0 * PI)) / (2.0 * log(10000.0));
  double lo_d = fmax(floor(cd_fast), 0.0);
  double hi_d = fmin(ceil(cd_slow), 63.0);
  float lo = (float)lo_d;
  float denom = (float)fmax(hi_d - lo_d, 0.001);

  // 1. cast hidden to bf16
  cast_f32_bf16<<<2048, 256, 0, stream>>>(hidden, hidB, T_SEQ * 4096 / 4);
  // 2. rope table
  rope_table<<<256, 256, 0, stream>>>(positions, cosT, sinT, lo, denom);
  // 3. Wqa^T ; q_lat = hid @ Wqa
  transpose_cast<<<dim3(4096 / 64, 1536 / 64), 256, 0, stream>>>(Wqa, Wt, 4096, 1536);
  gemm_bt<<<dim3(1536 / 128, 2048 / 128), 256, 0, stream>>>(hidB, Wt, qlat, 2048, 1536, 4096);
  // 4. rmsnorm q_lat
  rmsnorm_cast<<<2048, 256, 0, stream>>>(qlat, 1536, 1536, q_a_ln, qln, 1536);
  // 5. Wkva^T (pad 576->640) ; latent = hid @ Wkva
  transpose_cast<<<dim3(4096 / 64, 640 / 64), 256, 0, stream>>>(Wkva, Wt, 4096, 576);
  gemm_bt<<<dim3(640 / 128, 2048 / 128), 256, 0, stream>>>(hidB, Wt, latent, 2048, 640, 4096);
  // 6. rmsnorm kv_a ; rope k_pe
  rmsnorm_cast<<<2048, 256, 0, stream>>>(latent, 640, 512, kv_a_ln, kva, 512);
  rope_kpe<<<256, 256, 0, stream>>>(latent, cosT, sinT, kpe);
  // 7. Wqb^T ; qfull = qln @ Wqb
  transpose_cast<<<dim3(1536 / 64, 6144 / 64), 256, 0, stream>>>(Wqb, Wt, 1536, 6144);
  gemm_bt<<<dim3(6144 / 128, 2048 / 128), 256, 0, stream>>>(qln, Wt, qfull, 2048, 6144, 1536);
  // 8. Wkvb^T ; kvfull = kva @ Wkvb
  transpose_cast<<<dim3(512 / 64, 8192 / 64), 256, 0, stream>>>(Wkvb, Wt, 512, 8192);
  gemm_bt<<<dim3(8192 / 128, 2048 / 128), 256, 0, stream>>>(kva, Wt, kvfull, 2048, 8192, 512);
  // 9. build Q'(rope+scale), K'(nope|pe), Vt
  build_q<<<8192, 256, 0, stream>>>(qfull, cosT, sinT, Qp, scaling);
  build_k<<<8192, 256, 0, stream>>>(kvfull, kpe, Kp);
  build_vt<<<dim3(T_SEQ / 64, NHEAD), 256, 0, stream>>>(kvfull, Vt);
  // 10. attention
  flash_attn<<<dim3(T_SEQ / 16, NHEAD), 64, 0, stream>>>(Qp, Kp, Vt, attnb);
  // 11. Wo^T ; out = attn @ Wo
  transpose_cast<<<dim3(4096 / 64, 4096 / 64), 256, 0, stream>>>(Wo, Wt, 4096, 4096);
  gemm_bt<<<dim3(4096 / 128, 2048 / 128), 256, 0, stream>>>(attnb, Wt, out, 2048, 4096, 4096);
}

// Round 2
// 758.557 us; speedup vs baseline: 1.2651x; 1.2651x over previous
//
#include <hip/hip_runtime.h>
#include <math.h>

typedef __bf16 bf16x8 __attribute__((ext_vector_type(8)));
typedef float f32x4 __attribute__((ext_vector_type(4)));
typedef unsigned short u16;
typedef unsigned int u32;

#define T_SEQ 2048
#define NHEAD 32

// float -> bf16 bits, round-nearest-even
__device__ __forceinline__ u16 f2bu(float f){
  u32 u = __float_as_uint(f);
  u32 r = (u + 0x7fffu + ((u >> 16) & 1u)) >> 16;
  return (u16)r;
}

__device__ __forceinline__ void gload_lds16(const void* g, void* l){
  __builtin_amdgcn_global_load_lds((const __attribute__((address_space(1))) u32*)g,
                                   (__attribute__((address_space(3))) u32*)l, 16, 0, 0);
}

// ---------------- elementwise cast f32 -> bf16 (vector4) ----------------
__global__ void cast_f32_bf16(const float* __restrict__ in, u16* __restrict__ out, int n4){
  int i = blockIdx.x * blockDim.x + threadIdx.x;
  int stride = gridDim.x * blockDim.x;
  for (; i < n4; i += stride){
    float4 v = ((const float4*)in)[i];
    ushort4 o;
    o.x = f2bu(v.x); o.y = f2bu(v.y); o.z = f2bu(v.z); o.w = f2bu(v.w);
    ((ushort4*)out)[i] = o;
  }
}

// ---------------- transpose + cast: src f32 (K x N) -> dst bf16 (Npad x K) ----------------
__global__ void transpose_cast(const float* __restrict__ src, u16* __restrict__ dst,
                               int K, int N){
  __shared__ float tile[64][65];
  int k0 = blockIdx.x * 64, n0 = blockIdx.y * 64;
  int lr = threadIdx.x >> 6, lc = threadIdx.x & 63;
  #pragma unroll
  for (int i = 0; i < 16; i++){
    int r = lr * 16 + i;
    int n = n0 + lc;
    float v = (n < N) ? src[(size_t)(k0 + r) * N + n] : 0.f;
    tile[r][lc] = v;
  }
  __syncthreads();
  #pragma unroll
  for (int i = 0; i < 16; i++){
    int nr = lr * 16 + i;
    dst[(size_t)(n0 + nr) * K + k0 + lc] = f2bu(tile[lc][nr]);
  }
}

// ---------------- YaRN rope table ----------------
__global__ void rope_table(const int* __restrict__ positions, float* __restrict__ cosT,
                           float* __restrict__ sinT, float lo, float denom){
  int idx = blockIdx.x * blockDim.x + threadIdx.x;
  if (idx >= T_SEQ * 32) return;
  int t = idx >> 5, i = idx & 31;
  float pf = powf(10000.f, (float)i / 32.f);
  float inv_extra = 1.f / pf;
  float inv_inter = 1.f / (40.f * pf);
  float ramp = fminf(fmaxf(((float)i - lo) / denom, 0.f), 1.f);
  float invf = inv_inter * ramp + inv_extra * (1.f - ramp);
  float fr = (float)positions[t] * invf;
  cosT[idx] = cosf(fr);
  sinT[idx] = sinf(fr);
}

// ---------------- rmsnorm (f32 in, bf16 out) ----------------
__global__ void rmsnorm_cast(const float* __restrict__ in, int istride, int n,
                             const float* __restrict__ w, u16* __restrict__ out, int ostride){
  int row = blockIdx.x;
  const float* x = in + (size_t)row * istride;
  float ss = 0.f;
  for (int c = threadIdx.x; c < n; c += blockDim.x){ float v = x[c]; ss += v * v; }
  #pragma unroll
  for (int off = 1; off < 64; off <<= 1) ss += __shfl_xor(ss, off);
  __shared__ float wsum[4];
  if ((threadIdx.x & 63) == 0) wsum[threadIdx.x >> 6] = ss;
  __syncthreads();
  float tot = wsum[0] + wsum[1] + wsum[2] + wsum[3];
  float scale = rsqrtf(tot / (float)n + 1e-6f);
  for (int c = threadIdx.x; c < n; c += blockDim.x)
    out[(size_t)row * ostride + c] = f2bu(x[c] * scale * w[c]);
}

// ---------------- rope on k_pe ----------------
__global__ void rope_kpe(const float* __restrict__ latent, const float* __restrict__ cosT,
                         const float* __restrict__ sinT, u16* __restrict__ kpe){
  int idx = blockIdx.x * blockDim.x + threadIdx.x;
  if (idx >= T_SEQ * 32) return;
  int t = idx >> 5, i = idx & 31;
  float x1 = latent[(size_t)t * 640 + 512 + 2 * i];
  float x2 = latent[(size_t)t * 640 + 512 + 2 * i + 1];
  float c = cosT[idx], s = sinT[idx];
  kpe[t * 64 + 2 * i]     = f2bu(x1 * c - x2 * s);
  kpe[t * 64 + 2 * i + 1] = f2bu(x2 * c + x1 * s);
}

// ---------------- build Q' (H,T,192) bf16 ----------------
__global__ void build_q(const float* __restrict__ qfull, const float* __restrict__ cosT,
                        const float* __restrict__ sinT, u16* __restrict__ Qp, float scaling){
  const int total = NHEAD * T_SEQ * 192;
  for (int idx = blockIdx.x * blockDim.x + threadIdx.x; idx < total; idx += gridDim.x * blockDim.x){
    int h = idx / (T_SEQ * 192);
    int rem = idx - h * (T_SEQ * 192);
    int t = rem / 192, d = rem - t * 192;
    float v;
    if (d < 128){
      v = qfull[(size_t)t * 6144 + h * 192 + d];
    } else {
      int i = (d - 128) >> 1;
      float c = cosT[t * 32 + i], s = sinT[t * 32 + i];
      float x1 = qfull[(size_t)t * 6144 + h * 192 + 128 + 2 * i];
      float x2 = qfull[(size_t)t * 6144 + h * 192 + 128 + 2 * i + 1];
      v = ((d & 1) == 0) ? (x1 * c - x2 * s) : (x2 * c + x1 * s);
    }
    Qp[idx] = f2bu(v * scaling);
  }
}

// ---------------- build K' (H,T,192) bf16 ----------------
__global__ void build_k(const float* __restrict__ kvfull, const u16* __restrict__ kpe,
                        u16* __restrict__ Kp){
  const int total = NHEAD * T_SEQ * 192;
  for (int idx = blockIdx.x * blockDim.x + threadIdx.x; idx < total; idx += gridDim.x * blockDim.x){
    int h = idx / (T_SEQ * 192);
    int rem = idx - h * (T_SEQ * 192);
    int t = rem / 192, d = rem - t * 192;
    if (d < 128) Kp[idx] = f2bu(kvfull[(size_t)t * 8192 + h * 256 + d]);
    else         Kp[idx] = kpe[t * 64 + (d - 128)];
  }
}

// ---------------- build Vt (H,128,T) bf16 ----------------
__global__ void build_vt(const float* __restrict__ kvfull, u16* __restrict__ Vt){
  __shared__ u16 tile[128][72];
  int t0 = blockIdx.x * 64;
  int h = blockIdx.y;
  #pragma unroll
  for (int i = 0; i < 32; i++){
    int lin = threadIdx.x + i * 256;
    int tt = lin >> 7, dd = lin & 127;
    tile[dd][tt] = f2bu(kvfull[(size_t)(t0 + tt) * 8192 + h * 256 + 128 + dd]);
  }
  __syncthreads();
  #pragma unroll
  for (int i = 0; i < 32; i++){
    int lin = threadIdx.x + i * 256;
    int dd = lin >> 6, tt = lin & 63;
    Vt[(size_t)(h * 128 + dd) * T_SEQ + t0 + tt] = tile[dd][tt];
  }
}

// ---------------- GEMM: C[M,N] f32 = A[M,K]bf16 @ BT[N,K]bf16^T ----------------
__global__ __launch_bounds__(256) void gemm_bt(const u16* __restrict__ A, const u16* __restrict__ BT,
                                               float* __restrict__ C, int M, int N, int K){
  __shared__ __align__(1024) char lds[16384];
  char* ldsA = lds;
  char* ldsB = lds + 8192;
  const int tid = threadIdx.x;
  const int wave = tid >> 6, lane = tid & 63;
  const int lg = lane >> 4, lm = lane & 15;
  const int bm = blockIdx.y * 128, bn = blockIdx.x * 128;
  const int wr = (wave >> 1) * 64, wc = (wave & 1) * 64;
  f32x4 acc[4][4] = {};
  int srow[2], scol[2], soff[2];
  #pragma unroll
  for (int j = 0; j < 2; j++){
    int o = (wave * 2 + j) * 1024 + lane * 16;
    int row = o >> 6;
    int cg = ((o >> 4) & 3) ^ ((row >> 1) & 3);
    srow[j] = row; scol[j] = cg * 8; soff[j] = (wave * 2 + j) * 1024;
  }
  for (int k0 = 0; k0 < K; k0 += 32){
    #pragma unroll
    for (int j = 0; j < 2; j++){
      gload_lds16(A  + (size_t)(bm + srow[j]) * K + k0 + scol[j], ldsA + soff[j]);
      gload_lds16(BT + (size_t)(bn + srow[j]) * K + k0 + scol[j], ldsB + soff[j]);
    }
    __syncthreads();
    bf16x8 af[4], bfr[4];
    #pragma unroll
    for (int m = 0; m < 4; m++){
      int r = wr + m * 16 + lm;
      af[m] = *(const bf16x8*)(ldsA + r * 64 + ((lg ^ ((r >> 1) & 3)) << 4));
    }
    #pragma unroll
    for (int n = 0; n < 4; n++){
      int r = wc + n * 16 + lm;
      bfr[n] = *(const bf16x8*)(ldsB + r * 64 + ((lg ^ ((r >> 1) & 3)) << 4));
    }
    #pragma unroll
    for (int m = 0; m < 4; m++)
      #pragma unroll
      for (int n = 0; n < 4; n++)
        acc[m][n] = __builtin_amdgcn_mfma_f32_16x16x32_bf16(af[m], bfr[n], acc[m][n], 0, 0, 0);
    __syncthreads();
  }
  #pragma unroll
  for (int m = 0; m < 4; m++)
    #pragma unroll
    for (int n = 0; n < 4; n++)
      #pragma unroll
      for (int q = 0; q < 4; q++){
        int r = bm + wr + m * 16 + lg * 4 + q;
        int c = bn + wc + n * 16 + lm;
        C[(size_t)r * N + c] = acc[m][n][q];
      }
}

// ---------------- flash attention v2: 4 waves, QBLK=64, LDS double-buffered K/V ----------------
// grid (32 qtiles reversed, 32 heads), block 256.
// LDS: K 2x[32 rows][192] XOR-swizzled (chunk^=(r&7)), V 2x[128 d][32 t] (chunk^=((d>>1)&3)),
// P 4 waves x [16][40] u16.
__global__ __launch_bounds__(256) void flash_attn(const u16* __restrict__ Qp, const u16* __restrict__ Kp,
                                                  const u16* __restrict__ Vt, u16* __restrict__ attnb){
  const int qt = (int)gridDim.x - 1 - (int)blockIdx.x;   // heavy blocks first
  const int h = blockIdx.y;
  const int tid = threadIdx.x;
  const int wave = tid >> 6, lane = tid & 63;
  const int lg = lane >> 4, lm = lane & 15;
  const int qbase = qt * 64 + wave * 16;

  __shared__ __align__(1024) char lds[46080];
  char* ldsK = lds;                                   // 2 x 12288
  char* ldsV = lds + 24576;                           // 2 x 8192
  u16*  Pw   = (u16*)(lds + 40960 + wave * 1280);     // 16 x 40 u16 per wave

  const u16* KpH = Kp + (size_t)h * T_SEQ * 192;
  const u16* VtH = Vt + (size_t)h * 128 * T_SEQ;

  // per-lane staging offsets (linear LDS dest, inverse-swizzled global source)
  int kO[3], kSrc[3];
  #pragma unroll
  for (int j = 0; j < 3; j++){
    int o = (wave * 3 + j) * 1024 + lane * 16;
    int r = o / 384, c = (o % 384) >> 4;
    kO[j] = o; kSrc[j] = r * 192 + ((c ^ (r & 7)) << 3);
  }
  int vO[2], vSrc[2];
  #pragma unroll
  for (int j = 0; j < 2; j++){
    int o = (wave * 2 + j) * 1024 + lane * 16;
    int d = o >> 6, c = (o & 63) >> 4;
    vO[j] = o; vSrc[j] = d * T_SEQ + ((c ^ ((d >> 1) & 3)) << 3);
  }

  bf16x8 qf[6];
  const u16* Qbase = Qp + (size_t)(h * T_SEQ + qbase + lm) * 192 + lg * 8;
  #pragma unroll
  for (int dk = 0; dk < 6; dk++) qf[dk] = *(const bf16x8*)(Qbase + dk * 32);

  f32x4 o_[8] = {};
  float m_[4], l_[4];
  #pragma unroll
  for (int q = 0; q < 4; q++){ m_[q] = -3.0e38f; l_[q] = 0.f; }

  const int nt = 2 * qt + 2;

  // prologue: stage tile 0 into buffer 0
  #pragma unroll
  for (int j = 0; j < 3; j++) gload_lds16(KpH + kSrc[j], ldsK + kO[j]);
  #pragma unroll
  for (int j = 0; j < 2; j++) gload_lds16(VtH + vSrc[j], ldsV + vO[j]);

  for (int kt = 0; kt < nt; kt++){
    const int t0 = kt * 32;
    const int bsel = kt & 1;
    if (kt + 1 < nt){
      const int t1 = t0 + 32;
      char* Kd = ldsK + (bsel ^ 1) * 12288;
      char* Vd = ldsV + (bsel ^ 1) * 8192;
      #pragma unroll
      for (int j = 0; j < 3; j++) gload_lds16(KpH + (size_t)t1 * 192 + kSrc[j], Kd + kO[j]);
      #pragma unroll
      for (int j = 0; j < 2; j++) gload_lds16(VtH + vSrc[j] + t1, Vd + vO[j]);
      asm volatile("s_waitcnt vmcnt(5)" ::: "memory");   // tile-t loads done; 5 prefetches in flight
    } else {
      asm volatile("s_waitcnt vmcnt(0)" ::: "memory");
    }
    __builtin_amdgcn_sched_barrier(0);
    __builtin_amdgcn_s_barrier();

    const char* Kb = ldsK + bsel * 12288;
    const char* Vb = ldsV + bsel * 8192;

    // QK^T
    f32x4 s[2] = {};
    #pragma unroll
    for (int half = 0; half < 2; half++){
      const int r = half * 16 + lm;
      const int rbase = r * 384;
      const int rx = r & 7;
      #pragma unroll
      for (int dk = 0; dk < 6; dk++){
        bf16x8 kf = *(const bf16x8*)(Kb + rbase + (((dk * 4 + lg) ^ rx) << 4));
        s[half] = __builtin_amdgcn_mfma_f32_16x16x32_bf16(qf[dk], kf, s[half], 0, 0, 0);
      }
    }
    // causal mask
    #pragma unroll
    for (int half = 0; half < 2; half++)
      #pragma unroll
      for (int q = 0; q < 4; q++){
        int col = t0 + half * 16 + lm;
        int qrow = qbase + lg * 4 + q;
        if (col > qrow) s[half][q] = -3.0e38f;
      }
    // online softmax
    #pragma unroll
    for (int q = 0; q < 4; q++){
      float v = fmaxf(s[0][q], s[1][q]);
      #pragma unroll
      for (int off = 8; off; off >>= 1) v = fmaxf(v, __shfl_xor(v, off));
      float mn = fmaxf(m_[q], v);
      float alpha = (m_[q] <= -1.0e37f) ? 0.f : __expf(m_[q] - mn);
      float p0 = __expf(s[0][q] - mn);
      float p1 = __expf(s[1][q] - mn);
      float rs = p0 + p1;
      #pragma unroll
      for (int off = 8; off; off >>= 1) rs += __shfl_xor(rs, off);
      l_[q] = l_[q] * alpha + rs;
      m_[q] = mn;
      #pragma unroll
      for (int n = 0; n < 8; n++) o_[n][q] *= alpha;
      Pw[(lg * 4 + q) * 40 + lm]      = f2bu(p0);
      Pw[(lg * 4 + q) * 40 + 16 + lm] = f2bu(p1);
    }
    asm volatile("s_waitcnt lgkmcnt(0)" ::: "memory");
    __builtin_amdgcn_sched_barrier(0);
    bf16x8 pf = *(const bf16x8*)((const char*)Pw + lm * 80 + lg * 16);
    // P @ V from LDS
    #pragma unroll
    for (int n = 0; n < 8; n++){
      const int d = n * 16 + lm;
      bf16x8 vf = *(const bf16x8*)(Vb + d * 64 + ((lg ^ ((d >> 1) & 3)) << 4));
      o_[n] = __builtin_amdgcn_mfma_f32_16x16x32_bf16(pf, vf, o_[n], 0, 0, 0);
    }
    __builtin_amdgcn_s_barrier();   // all waves done reading buf before it is overwritten
  }

  float inv[4];
  #pragma unroll
  for (int q = 0; q < 4; q++) inv[q] = 1.f / l_[q];
  #pragma unroll
  for (int n = 0; n < 8; n++)
    #pragma unroll
    for (int q = 0; q < 4; q++){
      int r = qbase + lg * 4 + q;
      attnb[(size_t)r * 4096 + h * 128 + n * 16 + lm] = f2bu(o_[n][q] * inv[q]);
    }
}

// =====================================================================
extern "C" void kernel_launch(void* const* d_in, const int* in_sizes, int n_in,
                              void* d_out, int out_size, void* d_ws, size_t ws_size,
                              hipStream_t stream){
  const int*   positions = (const int*)d_in[0];
  const float* hidden    = (const float*)d_in[1];
  const float* Wqa       = (const float*)d_in[2];
  const float* q_a_ln    = (const float*)d_in[3];
  const float* Wqb       = (const float*)d_in[4];
  const float* Wkva      = (const float*)d_in[5];
  const float* kv_a_ln   = (const float*)d_in[6];
  const float* Wkvb      = (const float*)d_in[7];
  const float* Wo        = (const float*)d_in[8];
  float* out = (float*)d_out;
  char* ws = (char*)d_ws;

  const size_t o_hid   = 0;
  const size_t o_cos   = 16777216;
  const size_t o_sin   = 17039360;
  const size_t o_qlat  = 17301504;
  const size_t o_qln   = 29884416;
  const size_t o_lat   = 36175872;
  const size_t o_kva   = 41418752;
  const size_t o_kpe   = 43515904;
  const size_t o_W     = 43778048;
  const size_t o_qfull = 77332480;
  const size_t o_kvf   = 127664128;
  const size_t o_Qp    = 17301504;
  const size_t o_Kp    = 77332480;
  const size_t o_att   = 102498304;
  const size_t o_Vt    = 194772992;

  u16*   hidB   = (u16*)(ws + o_hid);
  float* cosT   = (float*)(ws + o_cos);
  float* sinT   = (float*)(ws + o_sin);
  float* qlat   = (float*)(ws + o_qlat);
  u16*   qln    = (u16*)(ws + o_qln);
  float* latent = (float*)(ws + o_lat);
  u16*   kva    = (u16*)(ws + o_kva);
  u16*   kpe    = (u16*)(ws + o_kpe);
  u16*   Wt     = (u16*)(ws + o_W);
  float* qfull  = (float*)(ws + o_qfull);
  float* kvfull = (float*)(ws + o_kvf);
  u16*   Qp     = (u16*)(ws + o_Qp);
  u16*   Kp     = (u16*)(ws + o_Kp);
  u16*   attnb  = (u16*)(ws + o_att);
  u16*   Vt     = (u16*)(ws + o_Vt);

  double mscale = 0.1 * log(40.0) + 1.0;
  float scaling = (float)(pow(192.0, -0.5) * mscale * mscale);
  const double PI = 3.14159265358979323846;
  double cd_fast = 64.0 * log(4096.0 / (32.0 * 2.0 * PI)) / (2.0 * log(10000.0));
  double cd_slow = 64.0 * log(4096.0 / ( 1.0 * 2.0 * PI)) / (2.0 * log(10000.0));
  double lo_d = fmax(floor(cd_fast), 0.0);
  double hi_d = fmin(ceil(cd_slow), 63.0);
  float lo = (float)lo_d;
  float denom = (float)fmax(hi_d - lo_d, 0.001);

  cast_f32_bf16<<<2048, 256, 0, stream>>>(hidden, hidB, T_SEQ * 4096 / 4);
  rope_table<<<256, 256, 0, stream>>>(positions, cosT, sinT, lo, denom);
  transpose_cast<<<dim3(4096 / 64, 1536 / 64), 256, 0, stream>>>(Wqa, Wt, 4096, 1536);
  gemm_bt<<<dim3(1536 / 128, 2048 / 128), 256, 0, stream>>>(hidB, Wt, qlat, 2048, 1536, 4096);
  rmsnorm_cast<<<2048, 256, 0, stream>>>(qlat, 1536, 1536, q_a_ln, qln, 1536);
  transpose_cast<<<dim3(4096 / 64, 640 / 64), 256, 0, stream>>>(Wkva, Wt, 4096, 576);
  gemm_bt<<<dim3(640 / 128, 2048 / 128), 256, 0, stream>>>(hidB, Wt, latent, 2048, 640, 4096);
  rmsnorm_cast<<<2048, 256, 0, stream>>>(latent, 640, 512, kv_a_ln, kva, 512);
  rope_kpe<<<256, 256, 0, stream>>>(latent, cosT, sinT, kpe);
  transpose_cast<<<dim3(1536 / 64, 6144 / 64), 256, 0, stream>>>(Wqb, Wt, 1536, 6144);
  gemm_bt<<<dim3(6144 / 128, 2048 / 128), 256, 0, stream>>>(qln, Wt, qfull, 2048, 6144, 1536);
  transpose_cast<<<dim3(512 / 64, 8192 / 64), 256, 0, stream>>>(Wkvb, Wt, 512, 8192);
  gemm_bt<<<dim3(8192 / 128, 2048 / 128), 256, 0, stream>>>(kva, Wt, kvfull, 2048, 8192, 512);
  build_q<<<8192, 256, 0, stream>>>(qfull, cosT, sinT, Qp, scaling);
  build_k<<<8192, 256, 0, stream>>>(kvfull, kpe, Kp);
  build_vt<<<dim3(T_SEQ / 64, NHEAD), 256, 0, stream>>>(kvfull, Vt);
  flash_attn<<<dim3(32, NHEAD), 256, 0, stream>>>(Qp, Kp, Vt, attnb);
  transpose_cast<<<dim3(4096 / 64, 4096 / 64), 256, 0, stream>>>(Wo, Wt, 4096, 4096);
  gemm_bt<<<dim3(4096 / 128, 2048 / 128), 256, 0, stream>>>(attnb, Wt, out, 2048, 4096, 4096);
}

// Round 3
// 526.759 us; speedup vs baseline: 1.8218x; 1.4400x over previous
//
#include <hip/hip_runtime.h>
#include <math.h>

typedef __bf16 bf16x8 __attribute__((ext_vector_type(8)));
typedef float f32x4 __attribute__((ext_vector_type(4)));
typedef unsigned short u16;
typedef unsigned int u32;

#define T_SEQ 2048
#define NHEAD 32

// float -> bf16 bits, round-nearest-even
__device__ __forceinline__ u16 f2bu(float f){
  u32 u = __float_as_uint(f);
  u32 r = (u + 0x7fffu + ((u >> 16) & 1u)) >> 16;
  return (u16)r;
}

__device__ __forceinline__ void gload_lds16(const void* g, void* l){
  __builtin_amdgcn_global_load_lds((const __attribute__((address_space(1))) u32*)g,
                                   (__attribute__((address_space(3))) u32*)l, 16, 0, 0);
}

// ---------------- elementwise cast f32 -> bf16 (vector4) ----------------
__global__ void cast_f32_bf16(const float* __restrict__ in, u16* __restrict__ out, int n4){
  int i = blockIdx.x * blockDim.x + threadIdx.x;
  int stride = gridDim.x * blockDim.x;
  for (; i < n4; i += stride){
    float4 v = ((const float4*)in)[i];
    ushort4 o;
    o.x = f2bu(v.x); o.y = f2bu(v.y); o.z = f2bu(v.z); o.w = f2bu(v.w);
    ((ushort4*)out)[i] = o;
  }
}

// ---------------- transpose + cast: src f32 (K x N) -> dst bf16 (Npad x K) ----------------
__global__ void transpose_cast(const float* __restrict__ src, u16* __restrict__ dst,
                               int K, int N){
  __shared__ float tile[64][65];
  int k0 = blockIdx.x * 64, n0 = blockIdx.y * 64;
  int lr = threadIdx.x >> 6, lc = threadIdx.x & 63;
  #pragma unroll
  for (int i = 0; i < 16; i++){
    int r = lr * 16 + i;
    int n = n0 + lc;
    float v = (n < N) ? src[(size_t)(k0 + r) * N + n] : 0.f;
    tile[r][lc] = v;
  }
  __syncthreads();
  #pragma unroll
  for (int i = 0; i < 16; i++){
    int nr = lr * 16 + i;
    dst[(size_t)(n0 + nr) * K + k0 + lc] = f2bu(tile[lc][nr]);
  }
}

// ---------------- YaRN rope table ----------------
__global__ void rope_table(const int* __restrict__ positions, float* __restrict__ cosT,
                           float* __restrict__ sinT, float lo, float denom){
  int idx = blockIdx.x * blockDim.x + threadIdx.x;
  if (idx >= T_SEQ * 32) return;
  int t = idx >> 5, i = idx & 31;
  float pf = powf(10000.f, (float)i / 32.f);
  float inv_extra = 1.f / pf;
  float inv_inter = 1.f / (40.f * pf);
  float ramp = fminf(fmaxf(((float)i - lo) / denom, 0.f), 1.f);
  float invf = inv_inter * ramp + inv_extra * (1.f - ramp);
  float fr = (float)positions[t] * invf;
  cosT[idx] = cosf(fr);
  sinT[idx] = sinf(fr);
}

// ---------------- rmsnorm (f32 in, bf16 out) ----------------
__global__ void rmsnorm_cast(const float* __restrict__ in, int istride, int n,
                             const float* __restrict__ w, u16* __restrict__ out, int ostride){
  int row = blockIdx.x;
  const float* x = in + (size_t)row * istride;
  float ss = 0.f;
  for (int c = threadIdx.x; c < n; c += blockDim.x){ float v = x[c]; ss += v * v; }
  #pragma unroll
  for (int off = 1; off < 64; off <<= 1) ss += __shfl_xor(ss, off);
  __shared__ float wsum[4];
  if ((threadIdx.x & 63) == 0) wsum[threadIdx.x >> 6] = ss;
  __syncthreads();
  float tot = wsum[0] + wsum[1] + wsum[2] + wsum[3];
  float scale = rsqrtf(tot / (float)n + 1e-6f);
  for (int c = threadIdx.x; c < n; c += blockDim.x)
    out[(size_t)row * ostride + c] = f2bu(x[c] * scale * w[c]);
}

// ---------------- rope on k_pe (reads strided cols of combined latent) ----------------
__global__ void rope_kpe(const float* __restrict__ lat, int lstride, int loff,
                         const float* __restrict__ cosT,
                         const float* __restrict__ sinT, u16* __restrict__ kpe){
  int idx = blockIdx.x * blockDim.x + threadIdx.x;
  if (idx >= T_SEQ * 32) return;
  int t = idx >> 5, i = idx & 31;
  float x1 = lat[(size_t)t * lstride + loff + 2 * i];
  float x2 = lat[(size_t)t * lstride + loff + 2 * i + 1];
  float c = cosT[idx], s = sinT[idx];
  kpe[t * 64 + 2 * i]     = f2bu(x1 * c - x2 * s);
  kpe[t * 64 + 2 * i + 1] = f2bu(x2 * c + x1 * s);
}

// ---------------- build Q' (H,T,192) bf16 ----------------
__global__ void build_q(const float* __restrict__ qfull, const float* __restrict__ cosT,
                        const float* __restrict__ sinT, u16* __restrict__ Qp, float scaling){
  const int total = NHEAD * T_SEQ * 192;
  for (int idx = blockIdx.x * blockDim.x + threadIdx.x; idx < total; idx += gridDim.x * blockDim.x){
    int h = idx / (T_SEQ * 192);
    int rem = idx - h * (T_SEQ * 192);
    int t = rem / 192, d = rem - t * 192;
    float v;
    if (d < 128){
      v = qfull[(size_t)t * 6144 + h * 192 + d];
    } else {
      int i = (d - 128) >> 1;
      float c = cosT[t * 32 + i], s = sinT[t * 32 + i];
      float x1 = qfull[(size_t)t * 6144 + h * 192 + 128 + 2 * i];
      float x2 = qfull[(size_t)t * 6144 + h * 192 + 128 + 2 * i + 1];
      v = ((d & 1) == 0) ? (x1 * c - x2 * s) : (x2 * c + x1 * s);
    }
    Qp[idx] = f2bu(v * scaling);
  }
}

// ---------------- build K' (H,T,192) bf16 ----------------
__global__ void build_k(const float* __restrict__ kvfull, const u16* __restrict__ kpe,
                        u16* __restrict__ Kp){
  const int total = NHEAD * T_SEQ * 192;
  for (int idx = blockIdx.x * blockDim.x + threadIdx.x; idx < total; idx += gridDim.x * blockDim.x){
    int h = idx / (T_SEQ * 192);
    int rem = idx - h * (T_SEQ * 192);
    int t = rem / 192, d = rem - t * 192;
    if (d < 128) Kp[idx] = f2bu(kvfull[(size_t)t * 8192 + h * 256 + d]);
    else         Kp[idx] = kpe[t * 64 + (d - 128)];
  }
}

// ---------------- build Vt (H,128,T) bf16 ----------------
__global__ void build_vt(const float* __restrict__ kvfull, u16* __restrict__ Vt){
  __shared__ u16 tile[128][72];
  int t0 = blockIdx.x * 64;
  int h = blockIdx.y;
  #pragma unroll
  for (int i = 0; i < 32; i++){
    int lin = threadIdx.x + i * 256;
    int tt = lin >> 7, dd = lin & 127;
    tile[dd][tt] = f2bu(kvfull[(size_t)(t0 + tt) * 8192 + h * 256 + 128 + dd]);
  }
  __syncthreads();
  #pragma unroll
  for (int i = 0; i < 32; i++){
    int lin = threadIdx.x + i * 256;
    int dd = lin >> 6, tt = lin & 63;
    Vt[(size_t)(h * 128 + dd) * T_SEQ + t0 + tt] = tile[dd][tt];
  }
}

// ---------------- GEMM: C[M,N] f32 = A[M,K]bf16 @ BT[N,K]bf16^T ----------------
__global__ __launch_bounds__(256) void gemm_bt(const u16* __restrict__ A, const u16* __restrict__ BT,
                                               float* __restrict__ C, int M, int N, int K){
  __shared__ __align__(1024) char lds[16384];
  char* ldsA = lds;
  char* ldsB = lds + 8192;
  const int tid = threadIdx.x;
  const int wave = tid >> 6, lane = tid & 63;
  const int lg = lane >> 4, lm = lane & 15;
  const int bm = blockIdx.y * 128, bn = blockIdx.x * 128;
  const int wr = (wave >> 1) * 64, wc = (wave & 1) * 64;
  f32x4 acc[4][4] = {};
  int srow[2], scol[2], soff[2];
  #pragma unroll
  for (int j = 0; j < 2; j++){
    int o = (wave * 2 + j) * 1024 + lane * 16;
    int row = o >> 6;
    int cg = ((o >> 4) & 3) ^ ((row >> 1) & 3);
    srow[j] = row; scol[j] = cg * 8; soff[j] = (wave * 2 + j) * 1024;
  }
  for (int k0 = 0; k0 < K; k0 += 32){
    #pragma unroll
    for (int j = 0; j < 2; j++){
      gload_lds16(A  + (size_t)(bm + srow[j]) * K + k0 + scol[j], ldsA + soff[j]);
      gload_lds16(BT + (size_t)(bn + srow[j]) * K + k0 + scol[j], ldsB + soff[j]);
    }
    __syncthreads();
    bf16x8 af[4], bfr[4];
    #pragma unroll
    for (int m = 0; m < 4; m++){
      int r = wr + m * 16 + lm;
      af[m] = *(const bf16x8*)(ldsA + r * 64 + ((lg ^ ((r >> 1) & 3)) << 4));
    }
    #pragma unroll
    for (int n = 0; n < 4; n++){
      int r = wc + n * 16 + lm;
      bfr[n] = *(const bf16x8*)(ldsB + r * 64 + ((lg ^ ((r >> 1) & 3)) << 4));
    }
    #pragma unroll
    for (int m = 0; m < 4; m++)
      #pragma unroll
      for (int n = 0; n < 4; n++)
        acc[m][n] = __builtin_amdgcn_mfma_f32_16x16x32_bf16(af[m], bfr[n], acc[m][n], 0, 0, 0);
    __syncthreads();
  }
  #pragma unroll
  for (int m = 0; m < 4; m++)
    #pragma unroll
    for (int n = 0; n < 4; n++)
      #pragma unroll
      for (int q = 0; q < 4; q++){
        int r = bm + wr + m * 16 + lg * 4 + q;
        int c = bn + wc + n * 16 + lm;
        C[(size_t)r * N + c] = acc[m][n][q];
      }
}

// ---------------- flash attention v3 ----------------
// 8 waves (512 thr), QBLK=128 (16 rows/wave), KVBLK=64, K+V double-buffered in LDS,
// defer-max softmax with per-lane partial l, head->XCD swizzle (b%8 == h%8).
// LDS: K 2x24576 (row 384B, chunk^=(r&7)), V 2x16384 ([128d][64t], chunk^=(d&7)),
// P per wave [16][72] u16.
__global__ __launch_bounds__(512, 2) void flash_attn(const u16* __restrict__ Qp, const u16* __restrict__ Kp,
                                                     const u16* __restrict__ Vt, u16* __restrict__ attnb){
  const int b = blockIdx.x;
  const int h  = (b & 7) + 8 * ((b >> 3) & 3);
  const int qt = 15 - (b >> 5);                 // heavy blocks dispatched first
  const int tid = threadIdx.x;
  const int wave = tid >> 6, lane = tid & 63;
  const int lg = lane >> 4, lm = lane & 15;
  const int qbase = qt * 128 + wave * 16;

  __shared__ __align__(1024) char lds[100352];
  char* ldsK = lds;                                  // 2 x 24576
  char* ldsV = lds + 49152;                          // 2 x 16384
  u16*  Pw   = (u16*)(lds + 81920 + wave * 2304);    // [16][72]

  const u16* KpH = Kp + (size_t)h * T_SEQ * 192;
  const u16* VtH = Vt + (size_t)h * 128 * T_SEQ;

  // DMA decode: linear LDS dest, inverse-swizzled global source
  int kO[3], kSrc[3];
  #pragma unroll
  for (int j = 0; j < 3; j++){
    int o = (tid + 512 * j) * 16;
    int r = o / 384, c = (o % 384) >> 4;
    kO[j] = o; kSrc[j] = r * 192 + ((c ^ (r & 7)) << 3);
  }
  int vO[2], vSrc[2];
  #pragma unroll
  for (int j = 0; j < 2; j++){
    int o = (tid + 512 * j) * 16;
    int d = o >> 7, c = (o & 127) >> 4;
    vO[j] = o; vSrc[j] = d * T_SEQ + ((c ^ (d & 7)) << 3);
  }

  bf16x8 qf[6];
  const u16* Qbase = Qp + (size_t)(h * T_SEQ + qbase + lm) * 192 + lg * 8;
  #pragma unroll
  for (int dk = 0; dk < 6; dk++) qf[dk] = *(const bf16x8*)(Qbase + dk * 32);

  f32x4 o_[8] = {};
  float m_[4], l_[4];
  #pragma unroll
  for (int q = 0; q < 4; q++){ m_[q] = -3.0e38f; l_[q] = 0.f; }

  const int nt = 2 * qt + 2;

  // prologue: stage tile 0 into buffer 0
  #pragma unroll
  for (int j = 0; j < 3; j++) gload_lds16(KpH + kSrc[j], ldsK + kO[j]);
  #pragma unroll
  for (int j = 0; j < 2; j++) gload_lds16(VtH + vSrc[j], ldsV + vO[j]);

  for (int kt = 0; kt < nt; kt++){
    const int t0 = kt * 64;
    const int bsel = kt & 1;
    asm volatile("s_waitcnt vmcnt(0)" ::: "memory");     // tile-t DMA (own wave) done
    __builtin_amdgcn_sched_barrier(0);
    __builtin_amdgcn_s_barrier();                        // all waves: tile-t resident, t-1 consumed
    if (kt + 1 < nt){
      const int t1 = t0 + 64;
      char* Kd = ldsK + (bsel ^ 1) * 24576;
      char* Vd = ldsV + (bsel ^ 1) * 16384;
      #pragma unroll
      for (int j = 0; j < 3; j++) gload_lds16(KpH + (size_t)t1 * 192 + kSrc[j], Kd + kO[j]);
      #pragma unroll
      for (int j = 0; j < 2; j++) gload_lds16(VtH + vSrc[j] + t1, Vd + vO[j]);
    }
    const char* Kb = ldsK + bsel * 24576;
    const char* Vb = ldsV + bsel * 16384;

    // QK^T: s[hh] covers k-cols hh*16..+15
    f32x4 s[4] = {};
    #pragma unroll
    for (int hh = 0; hh < 4; hh++){
      const int r = hh * 16 + lm;
      const int rb = r * 384, rx = r & 7;
      #pragma unroll
      for (int dk = 0; dk < 6; dk++){
        bf16x8 kf = *(const bf16x8*)(Kb + rb + (((dk * 4 + lg) ^ rx) << 4));
        s[hh] = __builtin_amdgcn_mfma_f32_16x16x32_bf16(qf[dk], kf, s[hh], 0, 0, 0);
      }
    }
    // causal mask
    #pragma unroll
    for (int hh = 0; hh < 4; hh++)
      #pragma unroll
      for (int q = 0; q < 4; q++){
        int col = t0 + hh * 16 + lm;
        int qrow = qbase + lg * 4 + q;
        if (col > qrow) s[hh][q] = -3.0e38f;
      }
    // defer-max online softmax
    float pm[4];
    #pragma unroll
    for (int q = 0; q < 4; q++)
      pm[q] = fmaxf(fmaxf(s[0][q], s[1][q]), fmaxf(s[2][q], s[3][q]));
    int ok = (pm[0] <= m_[0] + 8.f) & (pm[1] <= m_[1] + 8.f) &
             (pm[2] <= m_[2] + 8.f) & (pm[3] <= m_[3] + 8.f);
    if (!__all(ok)){
      #pragma unroll
      for (int q = 0; q < 4; q++){
        float v = pm[q];
        #pragma unroll
        for (int off = 8; off; off >>= 1) v = fmaxf(v, __shfl_xor(v, off));
        float mn = fmaxf(m_[q], v);
        float alpha = (m_[q] <= -1.0e37f) ? 0.f : __expf(m_[q] - mn);
        l_[q] *= alpha;
        #pragma unroll
        for (int n = 0; n < 8; n++) o_[n][q] *= alpha;
        m_[q] = mn;
      }
    }
    #pragma unroll
    for (int q = 0; q < 4; q++){
      #pragma unroll
      for (int hh = 0; hh < 4; hh++){
        float p = __expf(s[hh][q] - m_[q]);
        l_[q] += p;                                  // per-lane partial sum
        Pw[(lg * 4 + q) * 72 + hh * 16 + lm] = f2bu(p);
      }
    }
    asm volatile("s_waitcnt lgkmcnt(0)" ::: "memory");
    __builtin_amdgcn_sched_barrier(0);
    // P @ V
    #pragma unroll
    for (int ks = 0; ks < 2; ks++){
      bf16x8 pf = *(const bf16x8*)((const char*)Pw + lm * 144 + ks * 64 + lg * 16);
      #pragma unroll
      for (int n = 0; n < 8; n++){
        const int d = n * 16 + lm;
        bf16x8 vf = *(const bf16x8*)(Vb + d * 128 + (((ks * 4 + lg) ^ (d & 7)) << 4));
        o_[n] = __builtin_amdgcn_mfma_f32_16x16x32_bf16(pf, vf, o_[n], 0, 0, 0);
      }
    }
  }

  // final l reduction across the 16 lanes of each row group
  #pragma unroll
  for (int q = 0; q < 4; q++){
    #pragma unroll
    for (int off = 8; off; off >>= 1) l_[q] += __shfl_xor(l_[q], off);
  }
  float inv[4];
  #pragma unroll
  for (int q = 0; q < 4; q++) inv[q] = 1.f / l_[q];
  #pragma unroll
  for (int n = 0; n < 8; n++)
    #pragma unroll
    for (int q = 0; q < 4; q++){
      int r = qbase + lg * 4 + q;
      attnb[(size_t)r * 4096 + h * 128 + n * 16 + lm] = f2bu(o_[n][q] * inv[q]);
    }
}

// =====================================================================
extern "C" void kernel_launch(void* const* d_in, const int* in_sizes, int n_in,
                              void* d_out, int out_size, void* d_ws, size_t ws_size,
                              hipStream_t stream){
  const int*   positions = (const int*)d_in[0];
  const float* hidden    = (const float*)d_in[1];
  const float* Wqa       = (const float*)d_in[2];
  const float* q_a_ln    = (const float*)d_in[3];
  const float* Wqb       = (const float*)d_in[4];
  const float* Wkva      = (const float*)d_in[5];
  const float* kv_a_ln   = (const float*)d_in[6];
  const float* Wkvb      = (const float*)d_in[7];
  const float* Wo        = (const float*)d_in[8];
  float* out = (float*)d_out;
  char* ws = (char*)d_ws;

  // workspace layout (bytes); peak ~202 MiB
  const size_t o_hid   = 0;          // bf16 2048x4096
  const size_t o_cos   = 16777216;   // f32 2048x32
  const size_t o_sin   = 17039360;
  const size_t o_comb  = 17301504;   // f32 2048x2176 (qlat | latent | pad), ends 35127296
  const size_t o_qln   = 35127296;   // bf16 2048x1536, ends 41418752
  const size_t o_kva   = 41418752;   // bf16 2048x512, ends 43515904
  const size_t o_kpe   = 43515904;   // bf16 2048x64, ends 43778048
  const size_t o_W     = 43778048;   // bf16 weight scratch (<= 33.55 MB)
  const size_t o_qfull = 77332480;   // f32 2048x6144, ends 127664128
  const size_t o_kvf   = 127664128;  // f32 2048x8192, ends 194772992
  const size_t o_Qp    = 17301504;   // bf16 32x2048x192 (aliases comb+qln head), ends 42467328
  const size_t o_Kp    = 77332480;   // bf16 32x2048x192 (aliases qfull), ends 102498304
  const size_t o_att   = 102498304;  // bf16 2048x4096, ends 119275520
  const size_t o_Vt    = 194772992;  // bf16 32x128x2048, ends 211550208

  u16*   hidB   = (u16*)(ws + o_hid);
  float* cosT   = (float*)(ws + o_cos);
  float* sinT   = (float*)(ws + o_sin);
  float* comb   = (float*)(ws + o_comb);
  u16*   qln    = (u16*)(ws + o_qln);
  u16*   kva    = (u16*)(ws + o_kva);
  u16*   kpe    = (u16*)(ws + o_kpe);
  u16*   Wt     = (u16*)(ws + o_W);
  float* qfull  = (float*)(ws + o_qfull);
  float* kvfull = (float*)(ws + o_kvf);
  u16*   Qp     = (u16*)(ws + o_Qp);
  u16*   Kp     = (u16*)(ws + o_Kp);
  u16*   attnb  = (u16*)(ws + o_att);
  u16*   Vt     = (u16*)(ws + o_Vt);

  double mscale = 0.1 * log(40.0) + 1.0;
  float scaling = (float)(pow(192.0, -0.5) * mscale * mscale);
  const double PI = 3.14159265358979323846;
  double cd_fast = 64.0 * log(4096.0 / (32.0 * 2.0 * PI)) / (2.0 * log(10000.0));
  double cd_slow = 64.0 * log(4096.0 / ( 1.0 * 2.0 * PI)) / (2.0 * log(10000.0));
  double lo_d = fmax(floor(cd_fast), 0.0);
  double hi_d = fmin(ceil(cd_slow), 63.0);
  float lo = (float)lo_d;
  float denom = (float)fmax(hi_d - lo_d, 0.001);

  // 1. cast hidden; rope table
  cast_f32_bf16<<<2048, 256, 0, stream>>>(hidden, hidB, T_SEQ * 4096 / 4);
  rope_table<<<256, 256, 0, stream>>>(positions, cosT, sinT, lo, denom);
  // 2. fused Wqa|Wkva transpose into one 2176x4096 weight, one GEMM
  transpose_cast<<<dim3(4096 / 64, 1536 / 64), 256, 0, stream>>>(Wqa, Wt, 4096, 1536);
  transpose_cast<<<dim3(4096 / 64, 640 / 64), 256, 0, stream>>>(Wkva, Wt + (size_t)1536 * 4096, 4096, 576);
  gemm_bt<<<dim3(2176 / 128, 2048 / 128), 256, 0, stream>>>(hidB, Wt, comb, 2048, 2176, 4096);
  // 3. norms + k_pe rope off the combined buffer
  rmsnorm_cast<<<2048, 256, 0, stream>>>(comb, 2176, 1536, q_a_ln, qln, 1536);
  rmsnorm_cast<<<2048, 256, 0, stream>>>(comb + 1536, 2176, 512, kv_a_ln, kva, 512);
  rope_kpe<<<256, 256, 0, stream>>>(comb, 2176, 2048, cosT, sinT, kpe);
  // 4. qfull = qln @ Wqb
  transpose_cast<<<dim3(1536 / 64, 6144 / 64), 256, 0, stream>>>(Wqb, Wt, 1536, 6144);
  gemm_bt<<<dim3(6144 / 128, 2048 / 128), 256, 0, stream>>>(qln, Wt, qfull, 2048, 6144, 1536);
  // 5. kvfull = kva @ Wkvb
  transpose_cast<<<dim3(512 / 64, 8192 / 64), 256, 0, stream>>>(Wkvb, Wt, 512, 8192);
  gemm_bt<<<dim3(8192 / 128, 2048 / 128), 256, 0, stream>>>(kva, Wt, kvfull, 2048, 8192, 512);
  // 6. build Q', K', Vt
  build_q<<<8192, 256, 0, stream>>>(qfull, cosT, sinT, Qp, scaling);
  build_k<<<8192, 256, 0, stream>>>(kvfull, kpe, Kp);
  build_vt<<<dim3(T_SEQ / 64, NHEAD), 256, 0, stream>>>(kvfull, Vt);
  // 7. attention (512 blocks x 512 threads)
  flash_attn<<<512, 512, 0, stream>>>(Qp, Kp, Vt, attnb);
  // 8. out = attn @ Wo
  transpose_cast<<<dim3(4096 / 64, 4096 / 64), 256, 0, stream>>>(Wo, Wt, 4096, 4096);
  gemm_bt<<<dim3(4096 / 128, 2048 / 128), 256, 0, stream>>>(attnb, Wt, out, 2048, 4096, 4096);
}

// Round 4
// 441.783 us; speedup vs baseline: 2.1722x; 1.1923x over previous
//
#include <hip/hip_runtime.h>
#include <math.h>

typedef __bf16 bf16x8 __attribute__((ext_vector_type(8)));
typedef float f32x4 __attribute__((ext_vector_type(4)));
typedef unsigned short u16;
typedef unsigned int u32;

#define T_SEQ 2048
#define NHEAD 32

// float -> bf16 bits, round-nearest-even
__device__ __forceinline__ u16 f2bu(float f){
  u32 u = __float_as_uint(f);
  u32 r = (u + 0x7fffu + ((u >> 16) & 1u)) >> 16;
  return (u16)r;
}

__device__ __forceinline__ void gload_lds16(const void* g, void* l){
  __builtin_amdgcn_global_load_lds((const __attribute__((address_space(1))) u32*)g,
                                   (__attribute__((address_space(3))) u32*)l, 16, 0, 0);
}

// ---------------- elementwise cast f32 -> bf16 (vector4) ----------------
__global__ void cast_f32_bf16(const float* __restrict__ in, u16* __restrict__ out, int n4){
  int i = blockIdx.x * blockDim.x + threadIdx.x;
  int stride = gridDim.x * blockDim.x;
  for (; i < n4; i += stride){
    float4 v = ((const float4*)in)[i];
    ushort4 o;
    o.x = f2bu(v.x); o.y = f2bu(v.y); o.z = f2bu(v.z); o.w = f2bu(v.w);
    ((ushort4*)out)[i] = o;
  }
}

// ---------------- transpose + cast: src f32 (K x N) -> dst bf16 (Npad x K) ----------------
__global__ void transpose_cast(const float* __restrict__ src, u16* __restrict__ dst,
                               int K, int N){
  __shared__ float tile[64][65];
  int k0 = blockIdx.x * 64, n0 = blockIdx.y * 64;
  int lr = threadIdx.x >> 6, lc = threadIdx.x & 63;
  #pragma unroll
  for (int i = 0; i < 16; i++){
    int r = lr * 16 + i;
    int n = n0 + lc;
    float v = (n < N) ? src[(size_t)(k0 + r) * N + n] : 0.f;
    tile[r][lc] = v;
  }
  __syncthreads();
  #pragma unroll
  for (int i = 0; i < 16; i++){
    int nr = lr * 16 + i;
    dst[(size_t)(n0 + nr) * K + k0 + lc] = f2bu(tile[lc][nr]);
  }
}

// ---------------- YaRN rope table ----------------
__global__ void rope_table(const int* __restrict__ positions, float* __restrict__ cosT,
                           float* __restrict__ sinT, float lo, float denom){
  int idx = blockIdx.x * blockDim.x + threadIdx.x;
  if (idx >= T_SEQ * 32) return;
  int t = idx >> 5, i = idx & 31;
  float pf = powf(10000.f, (float)i / 32.f);
  float inv_extra = 1.f / pf;
  float inv_inter = 1.f / (40.f * pf);
  float ramp = fminf(fmaxf(((float)i - lo) / denom, 0.f), 1.f);
  float invf = inv_inter * ramp + inv_extra * (1.f - ramp);
  float fr = (float)positions[t] * invf;
  cosT[idx] = cosf(fr);
  sinT[idx] = sinf(fr);
}

// ---------------- rmsnorm (f32 in, bf16 out) ----------------
__global__ void rmsnorm_cast(const float* __restrict__ in, int istride, int n,
                             const float* __restrict__ w, u16* __restrict__ out, int ostride){
  int row = blockIdx.x;
  const float* x = in + (size_t)row * istride;
  float ss = 0.f;
  for (int c = threadIdx.x; c < n; c += blockDim.x){ float v = x[c]; ss += v * v; }
  #pragma unroll
  for (int off = 1; off < 64; off <<= 1) ss += __shfl_xor(ss, off);
  __shared__ float wsum[4];
  if ((threadIdx.x & 63) == 0) wsum[threadIdx.x >> 6] = ss;
  __syncthreads();
  float tot = wsum[0] + wsum[1] + wsum[2] + wsum[3];
  float scale = rsqrtf(tot / (float)n + 1e-6f);
  for (int c = threadIdx.x; c < n; c += blockDim.x)
    out[(size_t)row * ostride + c] = f2bu(x[c] * scale * w[c]);
}

// ---------------- rope on k_pe (reads strided cols of combined latent) ----------------
__global__ void rope_kpe(const float* __restrict__ lat, int lstride, int loff,
                         const float* __restrict__ cosT,
                         const float* __restrict__ sinT, u16* __restrict__ kpe){
  int idx = blockIdx.x * blockDim.x + threadIdx.x;
  if (idx >= T_SEQ * 32) return;
  int t = idx >> 5, i = idx & 31;
  float x1 = lat[(size_t)t * lstride + loff + 2 * i];
  float x2 = lat[(size_t)t * lstride + loff + 2 * i + 1];
  float c = cosT[idx], s = sinT[idx];
  kpe[t * 64 + 2 * i]     = f2bu(x1 * c - x2 * s);
  kpe[t * 64 + 2 * i + 1] = f2bu(x2 * c + x1 * s);
}

// ---------------- broadcast kpe into all heads' Kp[...,128..192) ----------------
__global__ void kpe_bcast(const u16* __restrict__ kpe, u16* __restrict__ Kp){
  int idx = blockIdx.x * blockDim.x + threadIdx.x;   // over NHEAD*T_SEQ*16 ushort4
  if (idx >= NHEAD * T_SEQ * 16) return;
  int h = idx >> 15;
  int rem = idx & 32767;
  int t = rem >> 4, j = rem & 15;
  ushort4 v = ((const ushort4*)(kpe + t * 64))[j];
  ((ushort4*)(Kp + (size_t)h * T_SEQ * 192 + (size_t)t * 192 + 128))[j] = v;
}

// ---------------- build Vt (H,128,T) bf16 from Vtmp (T, H*128) bf16 ----------------
__global__ void build_vt(const u16* __restrict__ Vtmp, u16* __restrict__ Vt){
  __shared__ u16 tile[128][72];
  int t0 = blockIdx.x * 64;
  int h = blockIdx.y;
  #pragma unroll
  for (int i = 0; i < 32; i++){
    int lin = threadIdx.x + i * 256;
    int tt = lin >> 7, dd = lin & 127;
    tile[dd][tt] = Vtmp[(size_t)(t0 + tt) * 4096 + h * 128 + dd];
  }
  __syncthreads();
  #pragma unroll
  for (int i = 0; i < 32; i++){
    int lin = threadIdx.x + i * 256;
    int dd = lin >> 6, tt = lin & 63;
    Vt[(size_t)(h * 128 + dd) * T_SEQ + t0 + tt] = tile[dd][tt];
  }
}

// ---------------- GEMM: C[M,N] = A[M,K]bf16 @ BT[N,K]bf16^T ----------------
// 128x128 tile, BK=32, 4 waves, double-buffered LDS, counted vmcnt, XCD swizzle.
// EPI 0: C f32.  EPI 1: Qp bf16 with fused RoPE(d>=128)+scaling (N=6144 layout).
// EPI 2: Kp bf16 (d<128) + Vtmp bf16 (d>=128) (N=8192 layout).
template<int EPI>
__global__ __launch_bounds__(256) void gemm_bt(const u16* __restrict__ A, const u16* __restrict__ BT,
                                               float* __restrict__ C, u16* __restrict__ O1,
                                               u16* __restrict__ O2,
                                               const float* __restrict__ cosT,
                                               const float* __restrict__ sinT,
                                               float scaling, int M, int N, int K){
  __shared__ __align__(1024) char lds[32768];   // A: buf0 0-8K, buf1 8-16K; B: 16-24K, 24-32K
  const int tid = threadIdx.x;
  const int wave = tid >> 6, lane = tid & 63;
  const int lg = lane >> 4, lm = lane & 15;

  // bijective XCD swizzle (m204)
  int gx = gridDim.x;
  int nwg = gx * gridDim.y;
  int orig = blockIdx.y * gx + blockIdx.x;
  int qq = nwg >> 3, rr = nwg & 7, xc = orig & 7, rest = orig >> 3;
  int wg = (xc < rr ? xc * (qq + 1) : rr * (qq + 1) + (xc - rr) * qq) + rest;
  const int bn = (wg % gx) * 128, bm = (wg / gx) * 128;

  const int wr = (wave >> 1) * 64, wc = (wave & 1) * 64;
  f32x4 acc[4][4] = {};
  int srow[2], scol[2], soff[2];
  #pragma unroll
  for (int j = 0; j < 2; j++){
    int o = (wave * 2 + j) * 1024 + lane * 16;
    int row = o >> 6;
    int cg = ((o >> 4) & 3) ^ ((row >> 1) & 3);
    srow[j] = row; scol[j] = cg * 8; soff[j] = (wave * 2 + j) * 1024;
  }

  // prologue: stage tile 0 into buf 0
  #pragma unroll
  for (int j = 0; j < 2; j++){
    gload_lds16(A  + (size_t)(bm + srow[j]) * K + scol[j], lds + soff[j]);
    gload_lds16(BT + (size_t)(bn + srow[j]) * K + scol[j], lds + 16384 + soff[j]);
  }

  int cur = 0;
  for (int k0 = 0; k0 < K; k0 += 32){
    if (k0 + 32 < K){
      char* dA = lds + (cur ^ 1) * 8192;
      char* dB = lds + 16384 + (cur ^ 1) * 8192;
      #pragma unroll
      for (int j = 0; j < 2; j++){
        gload_lds16(A  + (size_t)(bm + srow[j]) * K + k0 + 32 + scol[j], dA + soff[j]);
        gload_lds16(BT + (size_t)(bn + srow[j]) * K + k0 + 32 + scol[j], dB + soff[j]);
      }
      asm volatile("s_waitcnt vmcnt(4)" ::: "memory");
    } else {
      asm volatile("s_waitcnt vmcnt(0)" ::: "memory");
    }
    __builtin_amdgcn_sched_barrier(0);
    __builtin_amdgcn_s_barrier();          // cur tile resident for all waves

    const char* ldsA = lds + cur * 8192;
    const char* ldsB = lds + 16384 + cur * 8192;
    bf16x8 af[4], bfr[4];
    #pragma unroll
    for (int m = 0; m < 4; m++){
      int r = wr + m * 16 + lm;
      af[m] = *(const bf16x8*)(ldsA + r * 64 + ((lg ^ ((r >> 1) & 3)) << 4));
    }
    #pragma unroll
    for (int n = 0; n < 4; n++){
      int r = wc + n * 16 + lm;
      bfr[n] = *(const bf16x8*)(ldsB + r * 64 + ((lg ^ ((r >> 1) & 3)) << 4));
    }
    __builtin_amdgcn_s_setprio(1);
    #pragma unroll
    for (int m = 0; m < 4; m++)
      #pragma unroll
      for (int n = 0; n < 4; n++)
        acc[m][n] = __builtin_amdgcn_mfma_f32_16x16x32_bf16(af[m], bfr[n], acc[m][n], 0, 0, 0);
    __builtin_amdgcn_s_setprio(0);
    __builtin_amdgcn_s_barrier();          // all reads of cur done; safe to overwrite next iter
    cur ^= 1;
  }

  #pragma unroll
  for (int m = 0; m < 4; m++)
    #pragma unroll
    for (int n = 0; n < 4; n++)
      #pragma unroll
      for (int q = 0; q < 4; q++){
        int r = bm + wr + m * 16 + lg * 4 + q;
        int c = bn + wc + n * 16 + lm;
        float v = acc[m][n][q];
        if (EPI == 0){
          C[(size_t)r * N + c] = v;
        } else if (EPI == 1){
          float vp = __shfl_xor(v, 1);     // partner column (c^1)
          int h = c / 192, d = c - h * 192;
          float outv;
          if (d < 128) outv = v;
          else {
            int i = (d - 128) >> 1;
            float co = cosT[r * 32 + i], si = sinT[r * 32 + i];
            outv = (d & 1) ? (v * co + vp * si) : (v * co - vp * si);
          }
          O1[(size_t)h * T_SEQ * 192 + (size_t)r * 192 + d] = f2bu(outv * scaling);
        } else {
          int h = c >> 8, d = c & 255;
          if (d < 128) O1[(size_t)h * T_SEQ * 192 + (size_t)r * 192 + d] = f2bu(v);
          else         O2[(size_t)r * 4096 + h * 128 + (d - 128)] = f2bu(v);
        }
      }
}

// ---------------- flash attention v4 ----------------
// 8 waves (512 thr), QBLK=128 (16 rows/wave), KVBLK=64, K+V double-buffered LDS,
// defer-max softmax, paired q-strips (qt=s and 15-s) -> 256 uniform blocks (1/CU),
// head->XCD affinity via b&7.
__global__ __launch_bounds__(512, 1) void flash_attn(const u16* __restrict__ Qp, const u16* __restrict__ Kp,
                                                     const u16* __restrict__ Vt, u16* __restrict__ attnb){
  const int b = blockIdx.x;
  const int h = (b & 7) + 8 * ((b >> 3) & 3);
  const int s = b >> 5;                       // 0..7
  const int tid = threadIdx.x;
  const int wave = tid >> 6, lane = tid & 63;
  const int lg = lane >> 4, lm = lane & 15;

  __shared__ __align__(1024) char lds[100352];
  char* ldsK = lds;                                  // 2 x 24576
  char* ldsV = lds + 49152;                          // 2 x 16384
  u16*  Pw   = (u16*)(lds + 81920 + wave * 2304);    // [16][72]

  const u16* KpH = Kp + (size_t)h * T_SEQ * 192;
  const u16* VtH = Vt + (size_t)h * 128 * T_SEQ;

  // DMA decode: linear LDS dest, inverse-swizzled global source
  int kO[3], kSrc[3];
  #pragma unroll
  for (int j = 0; j < 3; j++){
    int o = (tid + 512 * j) * 16;
    int r = o / 384, c = (o % 384) >> 4;
    kO[j] = o; kSrc[j] = r * 192 + ((c ^ (r & 7)) << 3);
  }
  int vO[2], vSrc[2];
  #pragma unroll
  for (int j = 0; j < 2; j++){
    int o = (tid + 512 * j) * 16;
    int d = o >> 7, c = (o & 127) >> 4;
    vO[j] = o; vSrc[j] = d * T_SEQ + ((c ^ (d & 7)) << 3);
  }

  #pragma unroll 1
  for (int rep = 0; rep < 2; rep++){
    const int qt = rep ? s : (15 - s);        // heavy strip first
    const int qbase = qt * 128 + wave * 16;
    const int nt = 2 * qt + 2;

    __syncthreads();   // previous strip's LDS reads fully done before restaging

    bf16x8 qf[6];
    const u16* Qbase = Qp + (size_t)(h * T_SEQ + qbase + lm) * 192 + lg * 8;
    #pragma unroll
    for (int dk = 0; dk < 6; dk++) qf[dk] = *(const bf16x8*)(Qbase + dk * 32);

    f32x4 o_[8] = {};
    float m_[4], l_[4];
    #pragma unroll
    for (int q = 0; q < 4; q++){ m_[q] = -3.0e38f; l_[q] = 0.f; }

    // prologue: stage tile 0 into buffer 0
    #pragma unroll
    for (int j = 0; j < 3; j++) gload_lds16(KpH + kSrc[j], ldsK + kO[j]);
    #pragma unroll
    for (int j = 0; j < 2; j++) gload_lds16(VtH + vSrc[j], ldsV + vO[j]);

    for (int kt = 0; kt < nt; kt++){
      const int t0 = kt * 64;
      const int bsel = kt & 1;
      asm volatile("s_waitcnt vmcnt(0)" ::: "memory");
      __builtin_amdgcn_sched_barrier(0);
      __builtin_amdgcn_s_barrier();
      if (kt + 1 < nt){
        const int t1 = t0 + 64;
        char* Kd = ldsK + (bsel ^ 1) * 24576;
        char* Vd = ldsV + (bsel ^ 1) * 16384;
        #pragma unroll
        for (int j = 0; j < 3; j++) gload_lds16(KpH + (size_t)t1 * 192 + kSrc[j], Kd + kO[j]);
        #pragma unroll
        for (int j = 0; j < 2; j++) gload_lds16(VtH + vSrc[j] + t1, Vd + vO[j]);
      }
      const char* Kb = ldsK + bsel * 24576;
      const char* Vb = ldsV + bsel * 16384;

      // QK^T
      f32x4 s_[4] = {};
      __builtin_amdgcn_s_setprio(1);
      #pragma unroll
      for (int hh = 0; hh < 4; hh++){
        const int r = hh * 16 + lm;
        const int rb = r * 384, rx = r & 7;
        #pragma unroll
        for (int dk = 0; dk < 6; dk++){
          bf16x8 kf = *(const bf16x8*)(Kb + rb + (((dk * 4 + lg) ^ rx) << 4));
          s_[hh] = __builtin_amdgcn_mfma_f32_16x16x32_bf16(qf[dk], kf, s_[hh], 0, 0, 0);
        }
      }
      __builtin_amdgcn_s_setprio(0);
      // causal mask
      #pragma unroll
      for (int hh = 0; hh < 4; hh++)
        #pragma unroll
        for (int q = 0; q < 4; q++){
          int col = t0 + hh * 16 + lm;
          int qrow = qbase + lg * 4 + q;
          if (col > qrow) s_[hh][q] = -3.0e38f;
        }
      // defer-max online softmax
      float pm[4];
      #pragma unroll
      for (int q = 0; q < 4; q++)
        pm[q] = fmaxf(fmaxf(s_[0][q], s_[1][q]), fmaxf(s_[2][q], s_[3][q]));
      int ok = (pm[0] <= m_[0] + 8.f) & (pm[1] <= m_[1] + 8.f) &
               (pm[2] <= m_[2] + 8.f) & (pm[3] <= m_[3] + 8.f);
      if (!__all(ok)){
        #pragma unroll
        for (int q = 0; q < 4; q++){
          float v = pm[q];
          #pragma unroll
          for (int off = 8; off; off >>= 1) v = fmaxf(v, __shfl_xor(v, off));
          float mn = fmaxf(m_[q], v);
          float alpha = (m_[q] <= -1.0e37f) ? 0.f : __expf(m_[q] - mn);
          l_[q] *= alpha;
          #pragma unroll
          for (int n = 0; n < 8; n++) o_[n][q] *= alpha;
          m_[q] = mn;
        }
      }
      #pragma unroll
      for (int q = 0; q < 4; q++){
        #pragma unroll
        for (int hh = 0; hh < 4; hh++){
          float p = __expf(s_[hh][q] - m_[q]);
          l_[q] += p;
          Pw[(lg * 4 + q) * 72 + hh * 16 + lm] = f2bu(p);
        }
      }
      asm volatile("s_waitcnt lgkmcnt(0)" ::: "memory");
      __builtin_amdgcn_sched_barrier(0);
      // P @ V
      __builtin_amdgcn_s_setprio(1);
      #pragma unroll
      for (int ks = 0; ks < 2; ks++){
        bf16x8 pf = *(const bf16x8*)((const char*)Pw + lm * 144 + ks * 64 + lg * 16);
        #pragma unroll
        for (int n = 0; n < 8; n++){
          const int d = n * 16 + lm;
          bf16x8 vf = *(const bf16x8*)(Vb + d * 128 + (((ks * 4 + lg) ^ (d & 7)) << 4));
          o_[n] = __builtin_amdgcn_mfma_f32_16x16x32_bf16(pf, vf, o_[n], 0, 0, 0);
        }
      }
      __builtin_amdgcn_s_setprio(0);
    }

    #pragma unroll
    for (int q = 0; q < 4; q++){
      #pragma unroll
      for (int off = 8; off; off >>= 1) l_[q] += __shfl_xor(l_[q], off);
    }
    float inv[4];
    #pragma unroll
    for (int q = 0; q < 4; q++) inv[q] = 1.f / l_[q];
    #pragma unroll
    for (int n = 0; n < 8; n++)
      #pragma unroll
      for (int q = 0; q < 4; q++){
        int r = qbase + lg * 4 + q;
        attnb[(size_t)r * 4096 + h * 128 + n * 16 + lm] = f2bu(o_[n][q] * inv[q]);
      }
  }
}

// =====================================================================
extern "C" void kernel_launch(void* const* d_in, const int* in_sizes, int n_in,
                              void* d_out, int out_size, void* d_ws, size_t ws_size,
                              hipStream_t stream){
  const int*   positions = (const int*)d_in[0];
  const float* hidden    = (const float*)d_in[1];
  const float* Wqa       = (const float*)d_in[2];
  const float* q_a_ln    = (const float*)d_in[3];
  const float* Wqb       = (const float*)d_in[4];
  const float* Wkva      = (const float*)d_in[5];
  const float* kv_a_ln   = (const float*)d_in[6];
  const float* Wkvb      = (const float*)d_in[7];
  const float* Wo        = (const float*)d_in[8];
  float* out = (float*)d_out;
  char* ws = (char*)d_ws;

  // workspace layout (bytes); peak ~178 MiB
  const size_t o_hid  = 0;          // bf16 2048x4096
  const size_t o_cos  = 16777216;   // f32 2048x32
  const size_t o_sin  = 17039360;
  const size_t o_comb = 17301504;   // f32 2048x2176, ends 35127296
  const size_t o_qln  = 35127296;   // bf16 2048x1536, ends 41418752
  const size_t o_kva  = 41418752;   // bf16 2048x512, ends 43515904
  const size_t o_kpe  = 43515904;   // bf16 2048x64, ends 43778048
  const size_t o_W    = 43778048;   // bf16 weight scratch <= 33.55MB, ends 77332480
  const size_t o_Qp   = 77332480;   // bf16 32x2048x192, ends 102498304
  const size_t o_Kp   = 102498304;  // bf16 32x2048x192, ends 127664128
  const size_t o_Vtmp = 127664128;  // bf16 2048x4096, ends 144441344
  const size_t o_Vt   = 144441344;  // bf16 32x128x2048, ends 161218560
  const size_t o_att  = 161218560;  // bf16 2048x4096, ends 177995776

  u16*   hidB = (u16*)(ws + o_hid);
  float* cosT = (float*)(ws + o_cos);
  float* sinT = (float*)(ws + o_sin);
  float* comb = (float*)(ws + o_comb);
  u16*   qln  = (u16*)(ws + o_qln);
  u16*   kva  = (u16*)(ws + o_kva);
  u16*   kpe  = (u16*)(ws + o_kpe);
  u16*   Wt   = (u16*)(ws + o_W);
  u16*   Qp   = (u16*)(ws + o_Qp);
  u16*   Kp   = (u16*)(ws + o_Kp);
  u16*   Vtmp = (u16*)(ws + o_Vtmp);
  u16*   Vt   = (u16*)(ws + o_Vt);
  u16*   attnb= (u16*)(ws + o_att);

  double mscale = 0.1 * log(40.0) + 1.0;
  float scaling = (float)(pow(192.0, -0.5) * mscale * mscale);
  const double PI = 3.14159265358979323846;
  double cd_fast = 64.0 * log(4096.0 / (32.0 * 2.0 * PI)) / (2.0 * log(10000.0));
  double cd_slow = 64.0 * log(4096.0 / ( 1.0 * 2.0 * PI)) / (2.0 * log(10000.0));
  double lo_d = fmax(floor(cd_fast), 0.0);
  double hi_d = fmin(ceil(cd_slow), 63.0);
  float lo = (float)lo_d;
  float denom = (float)fmax(hi_d - lo_d, 0.001);

  // 1. cast hidden; rope table
  cast_f32_bf16<<<2048, 256, 0, stream>>>(hidden, hidB, T_SEQ * 4096 / 4);
  rope_table<<<256, 256, 0, stream>>>(positions, cosT, sinT, lo, denom);
  // 2. fused Wqa|Wkva weight, one GEMM -> comb f32
  transpose_cast<<<dim3(4096 / 64, 1536 / 64), 256, 0, stream>>>(Wqa, Wt, 4096, 1536);
  transpose_cast<<<dim3(4096 / 64, 640 / 64), 256, 0, stream>>>(Wkva, Wt + (size_t)1536 * 4096, 4096, 576);
  gemm_bt<0><<<dim3(2176 / 128, 2048 / 128), 256, 0, stream>>>(hidB, Wt, comb, nullptr, nullptr,
                                                               nullptr, nullptr, 0.f, 2048, 2176, 4096);
  // 3. norms + k_pe rope
  rmsnorm_cast<<<2048, 256, 0, stream>>>(comb, 2176, 1536, q_a_ln, qln, 1536);
  rmsnorm_cast<<<2048, 256, 0, stream>>>(comb + 1536, 2176, 512, kv_a_ln, kva, 512);
  rope_kpe<<<256, 256, 0, stream>>>(comb, 2176, 2048, cosT, sinT, kpe);
  // 4. Qp = rope(qln @ Wqb) * scaling, fused epilogue
  transpose_cast<<<dim3(1536 / 64, 6144 / 64), 256, 0, stream>>>(Wqb, Wt, 1536, 6144);
  gemm_bt<1><<<dim3(6144 / 128, 2048 / 128), 256, 0, stream>>>(qln, Wt, nullptr, Qp, nullptr,
                                                               cosT, sinT, scaling, 2048, 6144, 1536);
  // 5. Kp(nope)+Vtmp = kva @ Wkvb, fused epilogue; then kpe broadcast; Vt transpose
  transpose_cast<<<dim3(512 / 64, 8192 / 64), 256, 0, stream>>>(Wkvb, Wt, 512, 8192);
  gemm_bt<2><<<dim3(8192 / 128, 2048 / 128), 256, 0, stream>>>(kva, Wt, nullptr, Kp, Vtmp,
                                                               nullptr, nullptr, 0.f, 2048, 8192, 512);
  kpe_bcast<<<NHEAD * T_SEQ * 16 / 256, 256, 0, stream>>>(kpe, Kp);
  build_vt<<<dim3(T_SEQ / 64, NHEAD), 256, 0, stream>>>(Vtmp, Vt);
  // 6. attention (256 uniform blocks, 1/CU)
  flash_attn<<<256, 512, 0, stream>>>(Qp, Kp, Vt, attnb);
  // 7. out = attn @ Wo
  transpose_cast<<<dim3(4096 / 64, 4096 / 64), 256, 0, stream>>>(Wo, Wt, 4096, 4096);
  gemm_bt<0><<<dim3(4096 / 128, 2048 / 128), 256, 0, stream>>>(attnb, Wt, out, nullptr, nullptr,
                                                               nullptr, nullptr, 0.f, 2048, 4096, 4096);
}